// Round 1
// baseline (221.531 us; speedup 1.0000x reference)
//
#include <hip/hip_runtime.h>
#include <stdint.h>

typedef float f32x4 __attribute__((ext_vector_type(4)));
typedef __bf16 bf16x8 __attribute__((ext_vector_type(8)));

#define NROW 16384
#define DM   1024
#define HID  128
#define K1   8192   // DM*8 features
#define K2   1024   // HID*8 features

__device__ __forceinline__ unsigned short f2bf(float f) {
  unsigned u = __builtin_bit_cast(unsigned, f);
  u += 0x7fffu + ((u >> 16) & 1u);
  return (unsigned short)(u >> 16);
}

__device__ __forceinline__ void g2l16(const void* g, void* l) {
  __builtin_amdgcn_global_load_lds(
      (const __attribute__((address_space(1))) unsigned int*)g,
      (__attribute__((address_space(3))) unsigned int*)l, 16, 0, 0);
}

// 8-feature expansion of one scalar: [silu_hi, B0..B5, silu_lo]
// B-splines: exact port of the reference Cox-de-Boor recursion, uniform grid
// grid[j] = (j-3)*(2/3) - 1, j = 0..9  (K=3, NUM=3)
__device__ __forceinline__ uint4 expand8(float v) {
  const float H = 2.0f / 3.0f;
  float xm[10];
#pragma unroll
  for (int j = 0; j < 10; ++j) xm[j] = v - ((float)(j - 3) * H - 1.0f);
  float B[9];
#pragma unroll
  for (int j = 0; j < 9; ++j) B[j] = (xm[j] >= 0.0f && xm[j + 1] < 0.0f) ? 1.0f : 0.0f;
#pragma unroll
  for (int d = 1; d <= 3; ++d) {
    const float inv = 1.0f / ((float)d * H);  // constant-folded
#pragma unroll
    for (int g = 0; g < 9 - d; ++g)
      B[g] = (xm[g] * B[g] - xm[g + d + 1] * B[g + 1]) * inv;
  }
  float sg = __frcp_rn(1.0f + __expf(-v));
  float s = v * sg;                                   // silu(v)
  unsigned short sh = f2bf(s);
  float slo = s - __builtin_bit_cast(float, ((unsigned)sh) << 16);
  union { uint4 u; unsigned short h[8]; } r;
  r.h[0] = sh;
#pragma unroll
  for (int g = 0; g < 6; ++g) r.h[g + 1] = f2bf(B[g]);
  r.h[7] = f2bf(slo);                                 // hi/lo split for precision
  return r.u;
}

// ---- weight prep: W1T[o][i*8+c] bf16, c0=scale_base (dup at c7), c1..6=coef*sp
__global__ void kan_prep_w1(const float* __restrict__ c1, const float* __restrict__ sb1,
                            const float* __restrict__ sp1, unsigned short* __restrict__ w1t) {
  const int t = blockIdx.x * 256 + threadIdx.x;     // 131072 threads
  const int o = t >> 10, i = t & 1023;
  const float sb = sb1[i * HID + o], sp = sp1[i * HID + o];
  const float* cf = c1 + (size_t)(i * HID + o) * 6;
  union { uint4 u; unsigned short h[8]; } r;
  const unsigned short b = f2bf(sb);
  r.h[0] = b; r.h[7] = b;
#pragma unroll
  for (int g = 0; g < 6; ++g) r.h[g + 1] = f2bf(cf[g] * sp);
  *(uint4*)(w1t + (size_t)o * K1 + i * 8) = r.u;
}

__global__ void kan_prep_w2(const float* __restrict__ c2, const float* __restrict__ sb2,
                            const float* __restrict__ sp2, unsigned short* __restrict__ w2t) {
  const int t = blockIdx.x * 256 + threadIdx.x;     // 131072 threads
  const int o = t >> 7, i = t & 127;
  const float sb = sb2[i * DM + o], sp = sp2[i * DM + o];
  const float* cf = c2 + (size_t)(i * DM + o) * 6;
  union { uint4 u; unsigned short h[8]; } r;
  const unsigned short b = f2bf(sb);
  r.h[0] = b; r.h[7] = b;
#pragma unroll
  for (int g = 0; g < 6; ++g) r.h[g + 1] = f2bf(cf[g] * sp);
  *(uint4*)(w2t + (size_t)o * K2 + i * 8) = r.u;
}

// ---- layer 1: fused expand(x) -> GEMM -> expand(y1) -> a2 (bf16)
// BM=64, BN=128(=full), BK=64. 4 waves, each 32x64. LDS: A 8KB + B 16KB, dbuf.
__global__ __launch_bounds__(256, 2) void kan_gemm1(
    const float* __restrict__ x, const unsigned short* __restrict__ w1t,
    unsigned short* __restrict__ a2) {
  __shared__ __align__(16) unsigned short lds[2 * 12288];  // per buf: A 4096 + B 8192 shorts
  const int tid = threadIdx.x;
  const int lane = tid & 63, w = tid >> 6;
  const int wm = w >> 1, wn = w & 1;
  const int m0 = blockIdx.x * 64;
  const int arow = tid >> 2, ac0 = (tid & 3) * 2;

  f32x4 acc[2][4];
#pragma unroll
  for (int a = 0; a < 2; ++a)
#pragma unroll
    for (int b = 0; b < 4; ++b) acc[a][b] = (f32x4){0.f, 0.f, 0.f, 0.f};

  const int NT = K1 / 64;  // 128 K-tiles

  auto stageB = [&](int kt, int buf) {
#pragma unroll
    for (int q = 0; q < 4; ++q) {
      const int r = (w * 4 + q) * 8 + (lane >> 3);
      const int slot = (lane & 7) ^ (lane >> 3);        // inverse-swizzled source
      g2l16(w1t + (size_t)r * K1 + kt * 64 + slot * 8,
            (char*)lds + buf * 24576 + 8192 + (w * 4 + q) * 1024);
    }
  };
  auto stageA = [&](float2 xv, int buf) {
    uint4 u0 = expand8(xv.x);
    uint4 u1 = expand8(xv.y);
    char* base = (char*)lds + buf * 24576;
    const int sw = (arow & 7) << 4;
    *(uint4*)(base + ((arow * 128 + ac0 * 16) ^ sw)) = u0;
    *(uint4*)(base + ((arow * 128 + (ac0 + 1) * 16) ^ sw)) = u1;
  };

  float2 xv = *(const float2*)(x + (size_t)(m0 + arow) * DM + ac0);
  stageB(0, 0);
  stageA(xv, 0);
  xv = *(const float2*)(x + (size_t)(m0 + arow) * DM + 8 + ac0);
  __syncthreads();

  for (int kt = 0; kt < NT; ++kt) {
    const int cur = kt & 1;
    if (kt + 1 < NT) {
      stageB(kt + 1, cur ^ 1);
      stageA(xv, cur ^ 1);
      const int nk = (kt + 2 < NT) ? kt + 2 : NT - 1;   // pipelined x load (reg)
      xv = *(const float2*)(x + (size_t)(m0 + arow) * DM + nk * 8 + ac0);
    }
    const char* ab = (const char*)lds + cur * 24576;
    const char* bb = ab + 8192;
#pragma unroll
    for (int ks = 0; ks < 2; ++ks) {
      bf16x8 af[2], bfr[4];
#pragma unroll
      for (int mi = 0; mi < 2; ++mi) {
        const int row = wm * 32 + mi * 16 + (lane & 15);
        af[mi] = *(const bf16x8*)(ab + ((row * 128 + ks * 64 + (lane >> 4) * 16) ^ ((row & 7) << 4)));
      }
#pragma unroll
      for (int ni = 0; ni < 4; ++ni) {
        const int col = wn * 64 + ni * 16 + (lane & 15);
        bfr[ni] = *(const bf16x8*)(bb + ((col * 128 + ks * 64 + (lane >> 4) * 16) ^ ((col & 7) << 4)));
      }
#pragma unroll
      for (int mi = 0; mi < 2; ++mi)
#pragma unroll
        for (int ni = 0; ni < 4; ++ni)
          acc[mi][ni] = __builtin_amdgcn_mfma_f32_16x16x32_bf16(af[mi], bfr[ni], acc[mi][ni], 0, 0, 0);
    }
    __syncthreads();
  }

  // epilogue: y1 -> 8 bf16 features -> a2[n][col*8+c]
#pragma unroll
  for (int mi = 0; mi < 2; ++mi)
#pragma unroll
    for (int r = 0; r < 4; ++r) {
      const int row = wm * 32 + mi * 16 + (lane >> 4) * 4 + r;
#pragma unroll
      for (int ni = 0; ni < 4; ++ni) {
        const int col = wn * 64 + ni * 16 + (lane & 15);
        uint4 u = expand8(acc[mi][ni][r]);
        *(uint4*)(a2 + (size_t)(m0 + row) * K2 + col * 8) = u;
      }
    }
}

// ---- layer 2: plain bf16 GEMM (16384x1024) @ (1024x1024)^T -> fp32 out
// BM=BN=128, BK=64. 4 waves, each 64x64. LDS 2*(16KB+16KB)=64KB -> 2 blocks/CU.
__global__ __launch_bounds__(256, 2) void kan_gemm2(
    const unsigned short* __restrict__ a2, const unsigned short* __restrict__ w2t,
    float* __restrict__ out) {
  __shared__ __align__(16) unsigned short lds[2 * 16384];
  const int tid = threadIdx.x;
  const int lane = tid & 63, w = tid >> 6;
  const int wm = w >> 1, wn = w & 1;
  const int mt = blockIdx.x & 127, nt = blockIdx.x >> 7;  // mt fastest: A-panel sharers on same XCD
  const int m0 = mt * 128, n0 = nt * 128;

  f32x4 acc[4][4];
#pragma unroll
  for (int a = 0; a < 4; ++a)
#pragma unroll
    for (int b = 0; b < 4; ++b) acc[a][b] = (f32x4){0.f, 0.f, 0.f, 0.f};

  auto stage = [&](int kt, int buf) {
#pragma unroll
    for (int q = 0; q < 4; ++q) {
      const int r = (w * 4 + q) * 8 + (lane >> 3);
      const int slot = (lane & 7) ^ (lane >> 3);
      g2l16(a2 + (size_t)(m0 + r) * K2 + kt * 64 + slot * 8,
            (char*)lds + buf * 32768 + (w * 4 + q) * 1024);
      g2l16(w2t + (size_t)(n0 + r) * K2 + kt * 64 + slot * 8,
            (char*)lds + buf * 32768 + 16384 + (w * 4 + q) * 1024);
    }
  };

  stage(0, 0);
  __syncthreads();
  for (int kt = 0; kt < 16; ++kt) {
    const int cur = kt & 1;
    if (kt + 1 < 16) stage(kt + 1, cur ^ 1);
    const char* ab = (const char*)lds + cur * 32768;
    const char* bb = ab + 16384;
#pragma unroll
    for (int ks = 0; ks < 2; ++ks) {
      bf16x8 af[4], bfr[4];
#pragma unroll
      for (int mi = 0; mi < 4; ++mi) {
        const int row = wm * 64 + mi * 16 + (lane & 15);
        af[mi] = *(const bf16x8*)(ab + ((row * 128 + ks * 64 + (lane >> 4) * 16) ^ ((row & 7) << 4)));
      }
#pragma unroll
      for (int ni = 0; ni < 4; ++ni) {
        const int col = wn * 64 + ni * 16 + (lane & 15);
        bfr[ni] = *(const bf16x8*)(bb + ((col * 128 + ks * 64 + (lane >> 4) * 16) ^ ((col & 7) << 4)));
      }
#pragma unroll
      for (int mi = 0; mi < 4; ++mi)
#pragma unroll
        for (int ni = 0; ni < 4; ++ni)
          acc[mi][ni] = __builtin_amdgcn_mfma_f32_16x16x32_bf16(af[mi], bfr[ni], acc[mi][ni], 0, 0, 0);
    }
    __syncthreads();
  }

#pragma unroll
  for (int mi = 0; mi < 4; ++mi)
#pragma unroll
    for (int r = 0; r < 4; ++r) {
      const int row = wm * 64 + mi * 16 + (lane >> 4) * 4 + r;
#pragma unroll
      for (int ni = 0; ni < 4; ++ni) {
        const int col = wn * 64 + ni * 16 + (lane & 15);
        out[(size_t)(m0 + row) * DM + n0 + col] = acc[mi][ni][r];
      }
    }
}

extern "C" void kernel_launch(void* const* d_in, const int* in_sizes, int n_in,
                              void* d_out, int out_size, void* d_ws, size_t ws_size,
                              hipStream_t stream) {
  const float* x   = (const float*)d_in[0];
  const float* c1  = (const float*)d_in[1];
  const float* sb1 = (const float*)d_in[2];
  const float* sp1 = (const float*)d_in[3];
  const float* c2  = (const float*)d_in[4];
  const float* sb2 = (const float*)d_in[5];
  const float* sp2 = (const float*)d_in[6];
  float* out = (float*)d_out;

  unsigned short* w1t = (unsigned short*)d_ws;            // 128*8192  = 2 MB
  unsigned short* w2t = w1t + (size_t)HID * K1;           // 1024*1024 = 2 MB
  unsigned short* a2  = w2t + (size_t)DM * K2;            // 16384*1024 = 32 MB

  kan_prep_w1<<<512, 256, 0, stream>>>(c1, sb1, sp1, w1t);
  kan_prep_w2<<<512, 256, 0, stream>>>(c2, sb2, sp2, w2t);
  kan_gemm1<<<NROW / 64, 256, 0, stream>>>(x, w1t, a2);
  kan_gemm2<<<(NROW / 128) * (DM / 128), 256, 0, stream>>>(a2, w2t, out);
}

// Round 2
// 147.333 us; speedup vs baseline: 1.5036x; 1.5036x over previous
//
#include <hip/hip_runtime.h>
#include <stdint.h>

typedef float f32x4 __attribute__((ext_vector_type(4)));
typedef __bf16 bf16x8 __attribute__((ext_vector_type(8)));

#define NROW 16384
#define DM   1024
#define HID  128
#define K1   8192   // DM*8 features
#define K2   1024   // HID*8 features

__device__ __forceinline__ unsigned short f2bf(float f) {
  unsigned u = __builtin_bit_cast(unsigned, f);
  u += 0x7fffu + ((u >> 16) & 1u);
  return (unsigned short)(u >> 16);
}

__device__ __forceinline__ void g2l16(const void* g, void* l) {
  __builtin_amdgcn_global_load_lds(
      (const __attribute__((address_space(1))) unsigned int*)g,
      (__attribute__((address_space(3))) unsigned int*)l, 16, 0, 0);
}

// 8-feature expansion: [silu_hi, B0..B5, silu_lo].
// Closed-form uniform cubic B-spline: knots g_j=(j-3)*(2/3)-1, j=0..9.
// In cell c (t=(x+3)*1.5, c=floor(t), u=t-c) only bases g=c-3..c are nonzero:
//   B_g = P_{c-g}(u),  P0=u^3/6, P1=(1+3u+3u^2-3u^3)/6, P2=(4-6u^2+3u^3)/6, P3=(1-u)^3/6.
// C^2 continuity makes cell misassignment at knot boundaries O(ulp)-harmless.
__device__ __forceinline__ bf16x8 expand8(float v) {
  const float t = (v + 3.0f) * 1.5f;
  const float cf = floorf(t);
  const float u = t - cf;
  const int c = (int)cf;
  const float u2 = u * u;
  const float u3 = u2 * u;
  const float omu = 1.0f - u;
  const float p0 = u3 * (1.0f / 6.0f);
  const float p1 = (1.0f / 6.0f) + 0.5f * u + 0.5f * u2 - 0.5f * u3;
  const float p2 = (4.0f / 6.0f) - u2 + 0.5f * u3;
  const float p3 = omu * omu * omu * (1.0f / 6.0f);
  float B[6];
#pragma unroll
  for (int g = 0; g < 6; ++g) {
    const int r = c - g;
    float b = (r == 3) ? p3 : 0.0f;
    b = (r == 2) ? p2 : b;
    b = (r == 1) ? p1 : b;
    b = (r == 0) ? p0 : b;
    B[g] = b;
  }
  const float s = v * __frcp_rn(1.0f + __expf(-v));  // silu
  const __bf16 sh = (__bf16)s;
  const float slo = s - (float)sh;                   // hi/lo split for precision
  bf16x8 r8;
  r8[0] = sh;
#pragma unroll
  for (int g = 0; g < 6; ++g) r8[g + 1] = (__bf16)B[g];
  r8[7] = (__bf16)slo;
  return r8;
}

// ---- weight prep: W1T[o][i*8+c] bf16, c0=scale_base (dup at c7), c1..6=coef*sp
__global__ void kan_prep_w1(const float* __restrict__ c1, const float* __restrict__ sb1,
                            const float* __restrict__ sp1, unsigned short* __restrict__ w1t) {
  const int t = blockIdx.x * 256 + threadIdx.x;     // 131072 threads
  const int o = t >> 10, i = t & 1023;
  const float sb = sb1[i * HID + o], sp = sp1[i * HID + o];
  const float* cf = c1 + (size_t)(i * HID + o) * 6;
  union { uint4 u; unsigned short h[8]; } r;
  const unsigned short b = f2bf(sb);
  r.h[0] = b; r.h[7] = b;
#pragma unroll
  for (int g = 0; g < 6; ++g) r.h[g + 1] = f2bf(cf[g] * sp);
  *(uint4*)(w1t + (size_t)o * K1 + i * 8) = r.u;
}

__global__ void kan_prep_w2(const float* __restrict__ c2, const float* __restrict__ sb2,
                            const float* __restrict__ sp2, unsigned short* __restrict__ w2t) {
  const int t = blockIdx.x * 256 + threadIdx.x;     // 131072 threads
  const int o = t >> 7, i = t & 127;
  const float sb = sb2[i * DM + o], sp = sp2[i * DM + o];
  const float* cf = c2 + (size_t)(i * DM + o) * 6;
  union { uint4 u; unsigned short h[8]; } r;
  const unsigned short b = f2bf(sb);
  r.h[0] = b; r.h[7] = b;
#pragma unroll
  for (int g = 0; g < 6; ++g) r.h[g + 1] = f2bf(cf[g] * sp);
  *(uint4*)(w2t + (size_t)o * K2 + i * 8) = r.u;
}

// ---- layer 1: fused expand(x) -> GEMM -> expand(y1) -> a2 (bf16)
// BM=64, BN=128(=full), BK=64. 512 threads = 8 waves (2x4), each wave 32x32.
// grid 256 -> 1 block/CU, 8 waves/CU = 2 waves/SIMD.
__global__ __launch_bounds__(512, 2) void kan_gemm1(
    const float* __restrict__ x, const unsigned short* __restrict__ w1t,
    unsigned short* __restrict__ a2) {
  __shared__ __align__(16) unsigned short lds[2 * 12288];  // per buf: A 4096 + B 8192 shorts
  const int tid = threadIdx.x;
  const int lane = tid & 63, w = tid >> 6;
  const int wm = w >> 2, wn = w & 3;          // 2x4 wave grid, 32x32 each
  const int m0 = blockIdx.x * 64;
  const int arow = tid >> 3, acol = tid & 7;  // 1 expand per thread per K-tile

  f32x4 acc[2][2];
#pragma unroll
  for (int a = 0; a < 2; ++a)
#pragma unroll
    for (int b = 0; b < 2; ++b) acc[a][b] = (f32x4){0.f, 0.f, 0.f, 0.f};

  const int NT = K1 / 64;  // 128 K-tiles

  auto stageB = [&](int kt, int buf) {
#pragma unroll
    for (int q = 0; q < 2; ++q) {
      const int g = w * 2 + q;                          // 16 groups x 8 rows
      const int r = g * 8 + (lane >> 3);
      const int slot = (lane & 7) ^ (lane >> 3);        // inverse-swizzled source
      g2l16(w1t + (size_t)r * K1 + kt * 64 + slot * 8,
            (char*)lds + buf * 24576 + 8192 + g * 1024);
    }
  };
  auto stageA = [&](float xv, int buf) {
    bf16x8 u = expand8(xv);
    char* base = (char*)lds + buf * 24576;
    *(bf16x8*)(base + ((arow * 128 + acol * 16) ^ ((arow & 7) << 4))) = u;
  };

  float xv = x[(size_t)(m0 + arow) * DM + acol];
  stageB(0, 0);
  stageA(xv, 0);
  xv = x[(size_t)(m0 + arow) * DM + 8 + acol];
  __syncthreads();

  for (int kt = 0; kt < NT; ++kt) {
    const int cur = kt & 1;
    if (kt + 1 < NT) {
      stageB(kt + 1, cur ^ 1);
      stageA(xv, cur ^ 1);
      const int nk = (kt + 2 < NT) ? kt + 2 : NT - 1;   // pipelined x load (reg)
      xv = x[(size_t)(m0 + arow) * DM + nk * 8 + acol];
    }
    const char* ab = (const char*)lds + cur * 24576;
    const char* bb = ab + 8192;
#pragma unroll
    for (int ks = 0; ks < 2; ++ks) {
      bf16x8 af[2], bfr[2];
#pragma unroll
      for (int mi = 0; mi < 2; ++mi) {
        const int row = wm * 32 + mi * 16 + (lane & 15);
        af[mi] = *(const bf16x8*)(ab + ((row * 128 + ks * 64 + (lane >> 4) * 16) ^ ((row & 7) << 4)));
      }
#pragma unroll
      for (int ni = 0; ni < 2; ++ni) {
        const int col = wn * 32 + ni * 16 + (lane & 15);
        bfr[ni] = *(const bf16x8*)(bb + ((col * 128 + ks * 64 + (lane >> 4) * 16) ^ ((col & 7) << 4)));
      }
#pragma unroll
      for (int mi = 0; mi < 2; ++mi)
#pragma unroll
        for (int ni = 0; ni < 2; ++ni)
          acc[mi][ni] = __builtin_amdgcn_mfma_f32_16x16x32_bf16(af[mi], bfr[ni], acc[mi][ni], 0, 0, 0);
    }
    __syncthreads();
  }

  // epilogue: y1 -> 8 bf16 features -> a2[n][col*8+c]
#pragma unroll
  for (int mi = 0; mi < 2; ++mi)
#pragma unroll
    for (int r = 0; r < 4; ++r) {
      const int row = wm * 32 + mi * 16 + (lane >> 4) * 4 + r;
#pragma unroll
      for (int ni = 0; ni < 2; ++ni) {
        const int col = wn * 32 + ni * 16 + (lane & 15);
        bf16x8 u = expand8(acc[mi][ni][r]);
        *(bf16x8*)(a2 + (size_t)(m0 + row) * K2 + col * 8) = u;
      }
    }
}

// ---- layer 2: plain bf16 GEMM (16384x1024) @ (1024x1024)^T -> fp32 out
// BM=BN=128, BK=64. 4 waves, each 64x64. LDS 2*(16KB+16KB)=64KB -> 2 blocks/CU.
__global__ __launch_bounds__(256, 2) void kan_gemm2(
    const unsigned short* __restrict__ a2, const unsigned short* __restrict__ w2t,
    float* __restrict__ out) {
  __shared__ __align__(16) unsigned short lds[2 * 16384];
  const int tid = threadIdx.x;
  const int lane = tid & 63, w = tid >> 6;
  const int wm = w >> 1, wn = w & 1;
  const int mt = blockIdx.x & 127, nt = blockIdx.x >> 7;  // mt fastest: A-panel sharers on same XCD
  const int m0 = mt * 128, n0 = nt * 128;

  f32x4 acc[4][4];
#pragma unroll
  for (int a = 0; a < 4; ++a)
#pragma unroll
    for (int b = 0; b < 4; ++b) acc[a][b] = (f32x4){0.f, 0.f, 0.f, 0.f};

  auto stage = [&](int kt, int buf) {
#pragma unroll
    for (int q = 0; q < 4; ++q) {
      const int r = (w * 4 + q) * 8 + (lane >> 3);
      const int slot = (lane & 7) ^ (lane >> 3);
      g2l16(a2 + (size_t)(m0 + r) * K2 + kt * 64 + slot * 8,
            (char*)lds + buf * 32768 + (w * 4 + q) * 1024);
      g2l16(w2t + (size_t)(n0 + r) * K2 + kt * 64 + slot * 8,
            (char*)lds + buf * 32768 + 16384 + (w * 4 + q) * 1024);
    }
  };

  stage(0, 0);
  __syncthreads();
  for (int kt = 0; kt < 16; ++kt) {
    const int cur = kt & 1;
    if (kt + 1 < 16) stage(kt + 1, cur ^ 1);
    const char* ab = (const char*)lds + cur * 32768;
    const char* bb = ab + 16384;
#pragma unroll
    for (int ks = 0; ks < 2; ++ks) {
      bf16x8 af[4], bfr[4];
#pragma unroll
      for (int mi = 0; mi < 4; ++mi) {
        const int row = wm * 64 + mi * 16 + (lane & 15);
        af[mi] = *(const bf16x8*)(ab + ((row * 128 + ks * 64 + (lane >> 4) * 16) ^ ((row & 7) << 4)));
      }
#pragma unroll
      for (int ni = 0; ni < 4; ++ni) {
        const int col = wn * 64 + ni * 16 + (lane & 15);
        bfr[ni] = *(const bf16x8*)(bb + ((col * 128 + ks * 64 + (lane >> 4) * 16) ^ ((col & 7) << 4)));
      }
#pragma unroll
      for (int mi = 0; mi < 4; ++mi)
#pragma unroll
        for (int ni = 0; ni < 4; ++ni)
          acc[mi][ni] = __builtin_amdgcn_mfma_f32_16x16x32_bf16(af[mi], bfr[ni], acc[mi][ni], 0, 0, 0);
    }
    __syncthreads();
  }

#pragma unroll
  for (int mi = 0; mi < 4; ++mi)
#pragma unroll
    for (int r = 0; r < 4; ++r) {
      const int row = wm * 64 + mi * 16 + (lane >> 4) * 4 + r;
#pragma unroll
      for (int ni = 0; ni < 4; ++ni) {
        const int col = wn * 64 + ni * 16 + (lane & 15);
        out[(size_t)(m0 + row) * DM + n0 + col] = acc[mi][ni][r];
      }
    }
}

extern "C" void kernel_launch(void* const* d_in, const int* in_sizes, int n_in,
                              void* d_out, int out_size, void* d_ws, size_t ws_size,
                              hipStream_t stream) {
  const float* x   = (const float*)d_in[0];
  const float* c1  = (const float*)d_in[1];
  const float* sb1 = (const float*)d_in[2];
  const float* sp1 = (const float*)d_in[3];
  const float* c2  = (const float*)d_in[4];
  const float* sb2 = (const float*)d_in[5];
  const float* sp2 = (const float*)d_in[6];
  float* out = (float*)d_out;

  unsigned short* w1t = (unsigned short*)d_ws;            // 128*8192  = 2 MB
  unsigned short* w2t = w1t + (size_t)HID * K1;           // 1024*1024 = 2 MB
  unsigned short* a2  = w2t + (size_t)DM * K2;            // 16384*1024 = 32 MB

  kan_prep_w1<<<512, 256, 0, stream>>>(c1, sb1, sp1, w1t);
  kan_prep_w2<<<512, 256, 0, stream>>>(c2, sb2, sp2, w2t);
  kan_gemm1<<<NROW / 64, 512, 0, stream>>>(x, w1t, a2);
  kan_gemm2<<<(NROW / 128) * (DM / 128), 256, 0, stream>>>(a2, w2t, out);
}

// Round 3
// 136.666 us; speedup vs baseline: 1.6210x; 1.0780x over previous
//
#include <hip/hip_runtime.h>
#include <stdint.h>

typedef float f32x4 __attribute__((ext_vector_type(4)));
typedef __bf16 bf16x8 __attribute__((ext_vector_type(8)));

#define NROW 16384
#define DM   1024
#define HID  128
#define K1   8192   // DM*8 features
#define K2   1024   // HID*8 features

__device__ __forceinline__ unsigned short f2bf(float f) {
  unsigned u = __builtin_bit_cast(unsigned, f);
  u += 0x7fffu + ((u >> 16) & 1u);
  return (unsigned short)(u >> 16);
}

__device__ __forceinline__ void g2l16(const void* g, void* l) {
  __builtin_amdgcn_global_load_lds(
      (const __attribute__((address_space(1))) unsigned int*)g,
      (__attribute__((address_space(3))) unsigned int*)l, 16, 0, 0);
}

// 8-feature expansion: [silu_hi, B0..B5, silu_lo].
// Closed-form uniform cubic B-spline: knots g_j=(j-3)*(2/3)-1, j=0..9.
// In cell c (t=(x+3)*1.5, c=floor(t), u=t-c) only bases g=c-3..c are nonzero:
//   B_g = P_{c-g}(u),  P0=u^3/6, P1=(1+3u+3u^2-3u^3)/6, P2=(4-6u^2+3u^3)/6, P3=(1-u)^3/6.
// C^2 continuity makes cell misassignment at knot boundaries O(ulp)-harmless.
__device__ __forceinline__ bf16x8 expand8(float v) {
  const float t = (v + 3.0f) * 1.5f;
  const float cf = floorf(t);
  const float u = t - cf;
  const int c = (int)cf;
  const float u2 = u * u;
  const float u3 = u2 * u;
  const float omu = 1.0f - u;
  const float p0 = u3 * (1.0f / 6.0f);
  const float p1 = (1.0f / 6.0f) + 0.5f * u + 0.5f * u2 - 0.5f * u3;
  const float p2 = (4.0f / 6.0f) - u2 + 0.5f * u3;
  const float p3 = omu * omu * omu * (1.0f / 6.0f);
  float B[6];
#pragma unroll
  for (int g = 0; g < 6; ++g) {
    const int r = c - g;
    float b = (r == 3) ? p3 : 0.0f;
    b = (r == 2) ? p2 : b;
    b = (r == 1) ? p1 : b;
    b = (r == 0) ? p0 : b;
    B[g] = b;
  }
  const float s = v * __frcp_rn(1.0f + __expf(-v));  // silu
  const __bf16 sh = (__bf16)s;
  const float slo = s - (float)sh;                   // hi/lo split for precision
  bf16x8 r8;
  r8[0] = sh;
#pragma unroll
  for (int g = 0; g < 6; ++g) r8[g + 1] = (__bf16)B[g];
  r8[7] = (__bf16)slo;
  return r8;
}

// ---- weight prep: W1T[o][i*8+c] bf16, c0=scale_base (dup at c7), c1..6=coef*sp
__global__ void kan_prep_w1(const float* __restrict__ c1, const float* __restrict__ sb1,
                            const float* __restrict__ sp1, unsigned short* __restrict__ w1t) {
  const int t = blockIdx.x * 256 + threadIdx.x;     // 131072 threads
  const int o = t >> 10, i = t & 1023;
  const float sb = sb1[i * HID + o], sp = sp1[i * HID + o];
  const float* cf = c1 + (size_t)(i * HID + o) * 6;
  union { uint4 u; unsigned short h[8]; } r;
  const unsigned short b = f2bf(sb);
  r.h[0] = b; r.h[7] = b;
#pragma unroll
  for (int g = 0; g < 6; ++g) r.h[g + 1] = f2bf(cf[g] * sp);
  *(uint4*)(w1t + (size_t)o * K1 + i * 8) = r.u;
}

__global__ void kan_prep_w2(const float* __restrict__ c2, const float* __restrict__ sb2,
                            const float* __restrict__ sp2, unsigned short* __restrict__ w2t) {
  const int t = blockIdx.x * 256 + threadIdx.x;     // 131072 threads
  const int o = t >> 7, i = t & 127;
  const float sb = sb2[i * DM + o], sp = sp2[i * DM + o];
  const float* cf = c2 + (size_t)(i * DM + o) * 6;
  union { uint4 u; unsigned short h[8]; } r;
  const unsigned short b = f2bf(sb);
  r.h[0] = b; r.h[7] = b;
#pragma unroll
  for (int g = 0; g < 6; ++g) r.h[g + 1] = f2bf(cf[g] * sp);
  *(uint4*)(w2t + (size_t)o * K2 + i * 8) = r.u;
}

// ---- layer 1: fused expand(x) -> GEMM -> expand(y1) -> a2 (bf16)
// BM=32, BN=128(=full), BK=64. 512 threads = 8 waves (2x4 of 16x32 tiles).
// grid 512 -> 2 blocks/CU (LDS 40KB), 16 waves/CU = 4 waves/SIMD with
// INDEPENDENT barriers. Role split: waves 0-3 expand A, waves 4-7 stage B.
__global__ __launch_bounds__(512, 4) void kan_gemm1(
    const float* __restrict__ x, const unsigned short* __restrict__ w1t,
    unsigned short* __restrict__ a2) {
  __shared__ __align__(16) unsigned short lds[2 * 10240];  // per buf: A 4KB + B 16KB
  const int tid = threadIdx.x;
  const int lane = tid & 63, w = tid >> 6;
  const int wm = w & 1, wn = (w >> 1) & 3;    // 2x4 wave grid, 16x32 each
  const int m0 = blockIdx.x * 32;
  const int arow = tid >> 3, acol = tid & 7;  // valid for tid < 256 (waves 0-3)

  f32x4 acc[2];
  acc[0] = (f32x4){0.f, 0.f, 0.f, 0.f};
  acc[1] = (f32x4){0.f, 0.f, 0.f, 0.f};

  const int NT = K1 / 64;  // 128 K-tiles

  auto stageB = [&](int kt, int buf) {        // waves 4-7: 16 groups x 8 rows
#pragma unroll
    for (int q = 0; q < 4; ++q) {
      const int g = (w - 4) * 4 + q;
      const int r = g * 8 + (lane >> 3);
      const int slot = (lane & 7) ^ (lane >> 3);        // inverse-swizzled source
      g2l16(w1t + (size_t)r * K1 + kt * 64 + slot * 8,
            (char*)lds + buf * 20480 + 4096 + g * 1024);
    }
  };
  auto stageA = [&](float xv, int buf) {      // waves 0-3: 1 expand per lane
    bf16x8 u = expand8(xv);
    char* base = (char*)lds + buf * 20480;
    *(bf16x8*)(base + ((arow * 128 + acol * 16) ^ ((arow & 7) << 4))) = u;
  };

  float xv = 0.f;
  if (w < 4) {
    xv = x[(size_t)(m0 + arow) * DM + acol];
    stageA(xv, 0);
    xv = x[(size_t)(m0 + arow) * DM + 8 + acol];
  } else {
    stageB(0, 0);
  }
  __syncthreads();

  for (int kt = 0; kt < NT; ++kt) {
    const int cur = kt & 1;
    if (kt + 1 < NT) {
      if (w < 4) {
        stageA(xv, cur ^ 1);
        const int nk = (kt + 2 < NT) ? kt + 2 : NT - 1;   // pipelined x load (reg)
        xv = x[(size_t)(m0 + arow) * DM + nk * 8 + acol];
      } else {
        stageB(kt + 1, cur ^ 1);
      }
    }
    const char* ab = (const char*)lds + cur * 20480;
    const char* bb = ab + 4096;
#pragma unroll
    for (int ks = 0; ks < 2; ++ks) {
      bf16x8 af, bfr[2];
      {
        const int row = wm * 16 + (lane & 15);
        af = *(const bf16x8*)(ab + ((row * 128 + ks * 64 + (lane >> 4) * 16) ^ ((row & 7) << 4)));
      }
#pragma unroll
      for (int ni = 0; ni < 2; ++ni) {
        const int col = wn * 32 + ni * 16 + (lane & 15);
        bfr[ni] = *(const bf16x8*)(bb + ((col * 128 + ks * 64 + (lane >> 4) * 16) ^ ((col & 7) << 4)));
      }
#pragma unroll
      for (int ni = 0; ni < 2; ++ni)
        acc[ni] = __builtin_amdgcn_mfma_f32_16x16x32_bf16(af, bfr[ni], acc[ni], 0, 0, 0);
    }
    __syncthreads();
  }

  // epilogue: y1 -> 8 bf16 features -> a2[n][col*8+c]
#pragma unroll
  for (int r = 0; r < 4; ++r) {
    const int row = wm * 16 + (lane >> 4) * 4 + r;
#pragma unroll
    for (int ni = 0; ni < 2; ++ni) {
      const int col = wn * 32 + ni * 16 + (lane & 15);
      bf16x8 u = expand8(acc[ni][r]);
      *(bf16x8*)(a2 + (size_t)(m0 + row) * K2 + col * 8) = u;
    }
  }
}

// ---- layer 2: plain bf16 GEMM (16384x1024) @ (1024x1024)^T -> fp32 out
// BM=BN=128, BK=64. 4 waves, each 64x64. LDS 2*(16KB+16KB)=64KB -> 2 blocks/CU.
__global__ __launch_bounds__(256, 2) void kan_gemm2(
    const unsigned short* __restrict__ a2, const unsigned short* __restrict__ w2t,
    float* __restrict__ out) {
  __shared__ __align__(16) unsigned short lds[2 * 16384];
  const int tid = threadIdx.x;
  const int lane = tid & 63, w = tid >> 6;
  const int wm = w >> 1, wn = w & 1;
  const int mt = blockIdx.x & 127, nt = blockIdx.x >> 7;  // mt fastest: A-panel sharers on same XCD
  const int m0 = mt * 128, n0 = nt * 128;

  f32x4 acc[4][4];
#pragma unroll
  for (int a = 0; a < 4; ++a)
#pragma unroll
    for (int b = 0; b < 4; ++b) acc[a][b] = (f32x4){0.f, 0.f, 0.f, 0.f};

  auto stage = [&](int kt, int buf) {
#pragma unroll
    for (int q = 0; q < 4; ++q) {
      const int r = (w * 4 + q) * 8 + (lane >> 3);
      const int slot = (lane & 7) ^ (lane >> 3);
      g2l16(a2 + (size_t)(m0 + r) * K2 + kt * 64 + slot * 8,
            (char*)lds + buf * 32768 + (w * 4 + q) * 1024);
      g2l16(w2t + (size_t)(n0 + r) * K2 + kt * 64 + slot * 8,
            (char*)lds + buf * 32768 + 16384 + (w * 4 + q) * 1024);
    }
  };

  stage(0, 0);
  __syncthreads();
  for (int kt = 0; kt < 16; ++kt) {
    const int cur = kt & 1;
    if (kt + 1 < 16) stage(kt + 1, cur ^ 1);
    const char* ab = (const char*)lds + cur * 32768;
    const char* bb = ab + 16384;
#pragma unroll
    for (int ks = 0; ks < 2; ++ks) {
      bf16x8 af[4], bfr[4];
#pragma unroll
      for (int mi = 0; mi < 4; ++mi) {
        const int row = wm * 64 + mi * 16 + (lane & 15);
        af[mi] = *(const bf16x8*)(ab + ((row * 128 + ks * 64 + (lane >> 4) * 16) ^ ((row & 7) << 4)));
      }
#pragma unroll
      for (int ni = 0; ni < 4; ++ni) {
        const int col = wn * 64 + ni * 16 + (lane & 15);
        bfr[ni] = *(const bf16x8*)(bb + ((col * 128 + ks * 64 + (lane >> 4) * 16) ^ ((col & 7) << 4)));
      }
#pragma unroll
      for (int mi = 0; mi < 4; ++mi)
#pragma unroll
        for (int ni = 0; ni < 4; ++ni)
          acc[mi][ni] = __builtin_amdgcn_mfma_f32_16x16x32_bf16(af[mi], bfr[ni], acc[mi][ni], 0, 0, 0);
    }
    __syncthreads();
  }

#pragma unroll
  for (int mi = 0; mi < 4; ++mi)
#pragma unroll
    for (int r = 0; r < 4; ++r) {
      const int row = wm * 64 + mi * 16 + (lane >> 4) * 4 + r;
#pragma unroll
      for (int ni = 0; ni < 4; ++ni) {
        const int col = wn * 64 + ni * 16 + (lane & 15);
        out[(size_t)(m0 + row) * DM + n0 + col] = acc[mi][ni][r];
      }
    }
}

extern "C" void kernel_launch(void* const* d_in, const int* in_sizes, int n_in,
                              void* d_out, int out_size, void* d_ws, size_t ws_size,
                              hipStream_t stream) {
  const float* x   = (const float*)d_in[0];
  const float* c1  = (const float*)d_in[1];
  const float* sb1 = (const float*)d_in[2];
  const float* sp1 = (const float*)d_in[3];
  const float* c2  = (const float*)d_in[4];
  const float* sb2 = (const float*)d_in[5];
  const float* sp2 = (const float*)d_in[6];
  float* out = (float*)d_out;

  unsigned short* w1t = (unsigned short*)d_ws;            // 128*8192  = 2 MB
  unsigned short* w2t = w1t + (size_t)HID * K1;           // 1024*1024 = 2 MB
  unsigned short* a2  = w2t + (size_t)DM * K2;            // 16384*1024 = 32 MB

  kan_prep_w1<<<512, 256, 0, stream>>>(c1, sb1, sp1, w1t);
  kan_prep_w2<<<512, 256, 0, stream>>>(c2, sb2, sp2, w2t);
  kan_gemm1<<<NROW / 32, 512, 0, stream>>>(x, w1t, a2);
  kan_gemm2<<<(NROW / 128) * (DM / 128), 256, 0, stream>>>(a2, w2t, out);
}

// Round 4
// 130.538 us; speedup vs baseline: 1.6971x; 1.0469x over previous
//
#include <hip/hip_runtime.h>
#include <stdint.h>

typedef float f32x4 __attribute__((ext_vector_type(4)));
typedef __bf16 bf16x8 __attribute__((ext_vector_type(8)));

#define NROW 16384
#define DM   1024
#define HID  128
#define K1   8192   // DM*8 features
#define K2   1024   // HID*8 features

__device__ __forceinline__ unsigned short f2bf(float f) {
  unsigned u = __builtin_bit_cast(unsigned, f);
  u += 0x7fffu + ((u >> 16) & 1u);
  return (unsigned short)(u >> 16);
}

__device__ __forceinline__ uint32_t pkbf(float lo, float hi) {
  return (uint32_t)f2bf(lo) | ((uint32_t)f2bf(hi) << 16);
}

__device__ __forceinline__ void g2l16(const void* g, void* l) {
  __builtin_amdgcn_global_load_lds(
      (const __attribute__((address_space(1))) unsigned int*)g,
      (__attribute__((address_space(3))) unsigned int*)l, 16, 0, 0);
}

// 8-feature expansion: [silu_hi, B0..B5, silu_lo].
// Uniform cubic B-spline, knots g_j=(j-3)*(2/3)-1 (j=0..9). Cell c=floor((v+3)*1.5),
// u=frac. Active bases: B_g = P_{c-g}, g=c-3..c. Scatter [p3,p2,p1,p0] (16b bf16
// slots, slot0=p3) into slots 1..6 of a 128-bit value via shift by (c-2)*16 bits:
// slot j receives P_{c+1-j} = B_{j-1}. c clamped to [-1,9]: out-of-grid -> all-zero
// B (exactly matches the reference recursion, which yields 0 outside [g0,g9)).
__device__ __forceinline__ bf16x8 expand8(float v) {
  const float t = (v + 3.0f) * 1.5f;
  const float cf = floorf(t);
  const float u = t - cf;
  int c = (int)cf;
  c = c < -1 ? -1 : c;
  c = c > 9 ? 9 : c;
  const float u2 = u * u, u3 = u2 * u, omu = 1.0f - u;
  const float p0 = u3 * (1.0f / 6.0f);
  const float p1 = (1.0f / 6.0f) + 0.5f * u + 0.5f * u2 - 0.5f * u3;
  const float p2 = (4.0f / 6.0f) - u2 + 0.5f * u3;
  const float p3 = omu * omu * omu * (1.0f / 6.0f);
  const uint64_t W = (uint64_t)pkbf(p3, p2) | ((uint64_t)pkbf(p1, p0) << 32);
  const int sa = (c - 2) * 16;                 // in [-48, 112]
  const int sl = sa & 63;
  const uint64_t t1 = W << sl;
  const uint64_t t2 = (W >> (63 - sl)) >> 1;   // == W >> (64-sl), defined at sl=0
  const uint64_t t3 = W >> ((-sa) & 63);
  const uint64_t L = sa < 0 ? t3 : (sa < 64 ? t1 : 0);
  const uint64_t H = sa < 0 ? 0  : (sa < 64 ? t2 : t1);
  const float s = v * __frcp_rn(1.0f + __expf(-v));   // silu
  const unsigned short sh = f2bf(s);
  const float shf = __builtin_bit_cast(float, (uint32_t)sh << 16);
  const unsigned short slo = f2bf(s - shf);           // hi/lo split for precision
  const uint32_t w0 = ((uint32_t)L & 0xffff0000u) | sh;
  const uint32_t w1 = (uint32_t)(L >> 32);
  const uint32_t w2 = (uint32_t)H;
  const uint32_t w3 = ((uint32_t)(H >> 32) & 0xffffu) | ((uint32_t)slo << 16);
  union { uint4 q; bf16x8 b; } r;
  r.q = (uint4){w0, w1, w2, w3};
  return r.b;
}

// ---- weight prep: W1T[o][i*8+c] bf16, c0=scale_base (dup at c7), c1..6=coef*sp
__global__ void kan_prep_w1(const float* __restrict__ c1, const float* __restrict__ sb1,
                            const float* __restrict__ sp1, unsigned short* __restrict__ w1t) {
  const int t = blockIdx.x * 256 + threadIdx.x;     // 131072 threads
  const int o = t >> 10, i = t & 1023;
  const float sb = sb1[i * HID + o], sp = sp1[i * HID + o];
  const float* cf = c1 + (size_t)(i * HID + o) * 6;
  union { uint4 u; unsigned short h[8]; } r;
  const unsigned short b = f2bf(sb);
  r.h[0] = b; r.h[7] = b;
#pragma unroll
  for (int g = 0; g < 6; ++g) r.h[g + 1] = f2bf(cf[g] * sp);
  *(uint4*)(w1t + (size_t)o * K1 + i * 8) = r.u;
}

__global__ void kan_prep_w2(const float* __restrict__ c2, const float* __restrict__ sb2,
                            const float* __restrict__ sp2, unsigned short* __restrict__ w2t) {
  const int t = blockIdx.x * 256 + threadIdx.x;     // 131072 threads
  const int o = t >> 7, i = t & 127;
  const float sb = sb2[i * DM + o], sp = sp2[i * DM + o];
  const float* cf = c2 + (size_t)(i * DM + o) * 6;
  union { uint4 u; unsigned short h[8]; } r;
  const unsigned short b = f2bf(sb);
  r.h[0] = b; r.h[7] = b;
#pragma unroll
  for (int g = 0; g < 6; ++g) r.h[g + 1] = f2bf(cf[g] * sp);
  *(uint4*)(w2t + (size_t)o * K2 + i * 8) = r.u;
}

// ---- layer 1: fused expand(x) -> GEMM partial -> yp[kh]
// BM=128, BN=128(full), BK=64, K-split 2. grid 256 = 128 mt x 2 kh, 512 thr.
// 8 waves: wk=w>>2 (K-half of tile), (wm,wn)=((w>>1)&1, w&1), wave-tile 64x64.
// A (expanded x) staged in LDS (dbuf 2x16KB, XOR-swizzled); B (W1T, L2-hot)
// loaded DIRECTLY to VGPRs, double-buffered one K-tile ahead.
__global__ __launch_bounds__(512, 2) void kan_gemm1(
    const float* __restrict__ x, const unsigned short* __restrict__ w1t,
    float* __restrict__ yp) {
  __shared__ __align__(16) char lds[65536];   // A dbuf = first 32KB; epilogue reduce = 64KB
  const int tid = threadIdx.x;
  const int lane = tid & 63, w = tid >> 6;
  const int wk = w >> 2, wm = (w >> 1) & 1, wn = w & 1;
  const int mt = blockIdx.x >> 1, kh = blockIdx.x & 1;
  const int m0 = mt * 128;
  const int arow = tid >> 2, acs = (tid & 3) * 2;   // A-stage: 128 rows x 4 col-pairs

  f32x4 acc[4][4];
#pragma unroll
  for (int a = 0; a < 4; ++a)
#pragma unroll
    for (int b = 0; b < 4; ++b) acc[a][b] = (f32x4){0.f, 0.f, 0.f, 0.f};

  const int bo = wn * 64 + (lane & 15);             // B frag row (o)
  const int bk = wk * 32 + (lane >> 4) * 8;         // B frag k-offset within tile

  auto loadB = [&](int kt, bf16x8* bfrag) {
#pragma unroll
    for (int ni = 0; ni < 4; ++ni)
      bfrag[ni] = *(const bf16x8*)(w1t + (size_t)(bo + ni * 16) * K1 + kh * 4096 + kt * 64 + bk);
  };
  auto stageA = [&](float2 xv, int buf) {
    bf16x8 u0 = expand8(xv.x);
    bf16x8 u1 = expand8(xv.y);
    char* base = lds + buf * 16384;
    const int sw = (arow & 7) << 4;
    *(bf16x8*)(base + ((arow * 128 + acs * 16) ^ sw)) = u0;
    *(bf16x8*)(base + ((arow * 128 + acs * 16 + 16) ^ sw)) = u1;
  };

  const float* xrow = x + (size_t)(m0 + arow) * DM + kh * 512 + acs;
  bf16x8 bcur[4], bnxt[4];
  float2 xv = *(const float2*)xrow;
  loadB(0, bcur);
  stageA(xv, 0);
  xv = *(const float2*)(xrow + 8);
  __syncthreads();

  const int NT = 64;  // K-tiles per half
  for (int kt = 0; kt < NT; ++kt) {
    const int cur = kt & 1;
    if (kt + 1 < NT) {
      loadB(kt + 1, bnxt);          // issue early: L2 latency hides under expand VALU
      stageA(xv, cur ^ 1);
      if (kt + 2 < NT) xv = *(const float2*)(xrow + (kt + 2) * 8);
    }
    const char* ab = lds + cur * 16384;
    bf16x8 af[4];
#pragma unroll
    for (int mi = 0; mi < 4; ++mi) {
      const int row = wm * 64 + mi * 16 + (lane & 15);
      af[mi] = *(const bf16x8*)(ab + ((row * 128 + wk * 64 + (lane >> 4) * 16) ^ ((row & 7) << 4)));
    }
#pragma unroll
    for (int mi = 0; mi < 4; ++mi)
#pragma unroll
      for (int ni = 0; ni < 4; ++ni)
        acc[mi][ni] = __builtin_amdgcn_mfma_f32_16x16x32_bf16(af[mi], bcur[ni], acc[mi][ni], 0, 0, 0);
    __syncthreads();
#pragma unroll
    for (int ni = 0; ni < 4; ++ni) bcur[ni] = bnxt[ni];
  }

  // cross-wk reduce via LDS (tile buffers dead; use full 64KB)
  if (wk == 1) {
    char* r = lds + (w & 3) * 16384;
#pragma unroll
    for (int mi = 0; mi < 4; ++mi)
#pragma unroll
      for (int ni = 0; ni < 4; ++ni)
        *(f32x4*)(r + (mi * 4 + ni) * 1024 + lane * 16) = acc[mi][ni];
  }
  __syncthreads();
  if (wk == 0) {
    const char* r = lds + w * 16384;
    float* yb = yp + (size_t)kh * NROW * HID;
#pragma unroll
    for (int mi = 0; mi < 4; ++mi)
#pragma unroll
      for (int ni = 0; ni < 4; ++ni) {
        f32x4 o = *(const f32x4*)(r + (mi * 4 + ni) * 1024 + lane * 16);
        o += acc[mi][ni];
        const int col = wn * 64 + ni * 16 + (lane & 15);
#pragma unroll
        for (int rr = 0; rr < 4; ++rr) {
          const int row = wm * 64 + mi * 16 + (lane >> 4) * 4 + rr;
          yb[(size_t)(m0 + row) * HID + col] = o[rr];
        }
      }
  }
}

// ---- combine K-halves + expand y1 -> a2 (bf16 features for layer 2)
__global__ void kan_combine(const float* __restrict__ yp, unsigned short* __restrict__ a2) {
  const size_t i = (size_t)blockIdx.x * 256 + threadIdx.x;   // 2,097,152 threads
  const float v = yp[i] + yp[i + (size_t)NROW * HID];
  bf16x8 u = expand8(v);
  *(bf16x8*)(a2 + i * 8) = u;
}

// ---- layer 2: plain bf16 GEMM (16384x1024) @ (1024x1024)^T -> fp32 out
// BM=BN=128, BK=64. 4 waves, each 64x64. LDS 2*(16KB+16KB)=64KB -> 2 blocks/CU.
__global__ __launch_bounds__(256, 2) void kan_gemm2(
    const unsigned short* __restrict__ a2, const unsigned short* __restrict__ w2t,
    float* __restrict__ out) {
  __shared__ __align__(16) unsigned short lds[2 * 16384];
  const int tid = threadIdx.x;
  const int lane = tid & 63, w = tid >> 6;
  const int wm = w >> 1, wn = w & 1;
  const int mt = blockIdx.x & 127, nt = blockIdx.x >> 7;  // mt fastest: A-panel sharers on same XCD
  const int m0 = mt * 128, n0 = nt * 128;

  f32x4 acc[4][4];
#pragma unroll
  for (int a = 0; a < 4; ++a)
#pragma unroll
    for (int b = 0; b < 4; ++b) acc[a][b] = (f32x4){0.f, 0.f, 0.f, 0.f};

  auto stage = [&](int kt, int buf) {
#pragma unroll
    for (int q = 0; q < 4; ++q) {
      const int r = (w * 4 + q) * 8 + (lane >> 3);
      const int slot = (lane & 7) ^ (lane >> 3);
      g2l16(a2 + (size_t)(m0 + r) * K2 + kt * 64 + slot * 8,
            (char*)lds + buf * 32768 + (w * 4 + q) * 1024);
      g2l16(w2t + (size_t)(n0 + r) * K2 + kt * 64 + slot * 8,
            (char*)lds + buf * 32768 + 16384 + (w * 4 + q) * 1024);
    }
  };

  stage(0, 0);
  __syncthreads();
  for (int kt = 0; kt < 16; ++kt) {
    const int cur = kt & 1;
    if (kt + 1 < 16) stage(kt + 1, cur ^ 1);
    const char* ab = (const char*)lds + cur * 32768;
    const char* bb = ab + 16384;
#pragma unroll
    for (int ks = 0; ks < 2; ++ks) {
      bf16x8 af[4], bfr[4];
#pragma unroll
      for (int mi = 0; mi < 4; ++mi) {
        const int row = wm * 64 + mi * 16 + (lane & 15);
        af[mi] = *(const bf16x8*)(ab + ((row * 128 + ks * 64 + (lane >> 4) * 16) ^ ((row & 7) << 4)));
      }
#pragma unroll
      for (int ni = 0; ni < 4; ++ni) {
        const int col = wn * 64 + ni * 16 + (lane & 15);
        bfr[ni] = *(const bf16x8*)(bb + ((col * 128 + ks * 64 + (lane >> 4) * 16) ^ ((col & 7) << 4)));
      }
#pragma unroll
      for (int mi = 0; mi < 4; ++mi)
#pragma unroll
        for (int ni = 0; ni < 4; ++ni)
          acc[mi][ni] = __builtin_amdgcn_mfma_f32_16x16x32_bf16(af[mi], bfr[ni], acc[mi][ni], 0, 0, 0);
    }
    __syncthreads();
  }

#pragma unroll
  for (int mi = 0; mi < 4; ++mi)
#pragma unroll
    for (int r = 0; r < 4; ++r) {
      const int row = wm * 64 + mi * 16 + (lane >> 4) * 4 + r;
#pragma unroll
      for (int ni = 0; ni < 4; ++ni) {
        const int col = wn * 64 + ni * 16 + (lane & 15);
        out[(size_t)(m0 + row) * DM + n0 + col] = acc[mi][ni][r];
      }
    }
}

extern "C" void kernel_launch(void* const* d_in, const int* in_sizes, int n_in,
                              void* d_out, int out_size, void* d_ws, size_t ws_size,
                              hipStream_t stream) {
  const float* x   = (const float*)d_in[0];
  const float* c1  = (const float*)d_in[1];
  const float* sb1 = (const float*)d_in[2];
  const float* sp1 = (const float*)d_in[3];
  const float* c2  = (const float*)d_in[4];
  const float* sb2 = (const float*)d_in[5];
  const float* sp2 = (const float*)d_in[6];
  float* out = (float*)d_out;

  unsigned short* w1t = (unsigned short*)d_ws;            // 128*8192   = 2 MB
  unsigned short* w2t = w1t + (size_t)HID * K1;           // 1024*1024  = 2 MB
  unsigned short* a2  = w2t + (size_t)DM * K2;            // 16384*1024 = 32 MB
  float*          yp  = (float*)(a2 + (size_t)NROW * K2); // 2*16384*128= 16 MB

  kan_prep_w1<<<512, 256, 0, stream>>>(c1, sb1, sp1, w1t);
  kan_prep_w2<<<512, 256, 0, stream>>>(c2, sb2, sp2, w2t);
  kan_gemm1<<<256, 512, 0, stream>>>(x, w1t, yp);
  kan_combine<<<NROW * HID / 256, 256, 0, stream>>>(yp, a2);
  kan_gemm2<<<(NROW / 128) * (DM / 128), 256, 0, stream>>>(a2, w2t, out);
}